// Round 9
// baseline (382.151 us; speedup 1.0000x reference)
//
#include <hip/hip_runtime.h>
#include <hip/hip_bf16.h>
#include <cstdint>
#include <cstddef>

// YatDense: out[m,n] = (y^2 / (|x_m|^2 + |w_n|^2 - 2y + eps)) * scale + bias[n]
//   y = x[m,:] . w[n,:]   GEMM M=16384, N=2048, K=2048 (B^T layout input)
// R12: deep-ring schedule. R11 proved memory traffic is NOT the constraint
// (FETCH 272->100MB, time +8us). Surviving hypothesis: 2-K-tile ring depth
// forces drains of 1-2-phase-old loads (<900cy HBM miss) -> latency exposed
// at every VM point. Fix: BK=32, seg=[128][32]=8KB, SIX half-slots per
// matrix (3 K-tiles, 96KB LDS). Stage tile u+2 during tile u: stage->read
// distance 4-5 phases; vmcnt(4) once per K-tile drains only 2-3-phase-old
// loads. Phase = {ds_reads; 2 async16; SBAR; lgkm0; setprio1; 16 MFMA;
// setprio0; [VM]; SBAR} (R6-proven discipline: lgkm0 before closing barrier
// makes reads globally complete -> 1-phase overwrite distance legal).
// Ledger: prologue tiles 0,1 (8 loads) + VM4 (keeps tile1) + SBAR.
// pE(u): read af[0..3]+bf[0..3]; stage A(u+2)h0,B(u+2)h0 -> slots sv*2.
// pO(u): read af[4..7]; stage A(u+2)h1,B(u+2)h1 -> sv*2+1; VM4 (u<KT-2
// else VM0) drains tile u+1 for pE(u+1). Overwrite target = tile u-1, dead
// since pO(u-1)'s lgkm0+SBAR. Slots: tile u -> (u%3)*2 + h.
// LDS swizzle (4-chunk rows): phys chunk = jch ^ ((row>>1)&3) -> 2-way only.
// No XCD swizzle (R11: -170MB FETCH but +8us). prep unchanged (R7).
// (Resubmitted unchanged after R8 infra timeout — never benched.)

typedef __bf16 bf16_t;
typedef __bf16 bf16x8 __attribute__((ext_vector_type(8)));
typedef __bf16 bf16x4 __attribute__((ext_vector_type(4)));
typedef float f32x4 __attribute__((ext_vector_type(4)));

constexpr int M_DIM = 16384;  // B*S
constexpr int N_DIM = 2048;   // F
constexpr int K_DIM = 2048;   // D
constexpr int BM = 256, BN = 256, BK = 32;
constexpr int KT = K_DIM / BK;  // 64 K-tiles
constexpr int SEG = 128 * 32;   // seg elements (8 KB)

__device__ __forceinline__ void async16(const bf16_t* g, bf16_t* l) {
    __builtin_amdgcn_global_load_lds(
        (const __attribute__((address_space(1))) void*)g,
        (__attribute__((address_space(3))) void*)l,
        16, 0, 0);
}

// ---------------------------------------------------------------------------
// prep: one WAVE per row; 8 rows per 256-thread block; grid 2304. (as R7)
// ---------------------------------------------------------------------------
__global__ __launch_bounds__(256) void prep_convert(const float* __restrict__ x,
                                                    const float* __restrict__ w,
                                                    bf16_t* __restrict__ xb,
                                                    bf16_t* __restrict__ wb,
                                                    float* __restrict__ xsq,
                                                    float* __restrict__ wsq) {
    const int lane = threadIdx.x & 63;
    const int wv = threadIdx.x >> 6;
    const int base = blockIdx.x * 8 + wv * 2;
#pragma unroll
    for (int it = 0; it < 2; ++it) {
        const int row = base + it;
        const float* src;
        bf16_t* dstb;
        float* dsts;
        if (row < M_DIM) {
            src = x + (size_t)row * K_DIM;
            dstb = xb + (size_t)row * K_DIM;
            dsts = xsq + row;
        } else {
            const int r = row - M_DIM;
            src = w + (size_t)r * K_DIM;
            dstb = wb + (size_t)r * K_DIM;
            dsts = wsq + r;
        }
        const float4* s4 = (const float4*)src;
        bf16x4* d4 = (bf16x4*)dstb;
        float s = 0.0f;
#pragma unroll
        for (int j = 0; j < 8; ++j) {
            const float4 a = s4[lane + j * 64];
            s += a.x * a.x + a.y * a.y + a.z * a.z + a.w * a.w;
            bf16x4 v = { (bf16_t)a.x, (bf16_t)a.y, (bf16_t)a.z, (bf16_t)a.w };
            d4[lane + j * 64] = v;
        }
#pragma unroll
        for (int off = 32; off > 0; off >>= 1) s += __shfl_down(s, off, 64);
        if (lane == 0) *dsts = s;
    }
}

// ---------------------------------------------------------------------------
// Deep-ring GEMM + Yat epilogue, one 256x256 tile per block.
// ---------------------------------------------------------------------------
__global__ __launch_bounds__(512, 2) void yat_gemm(const bf16_t* __restrict__ A,   // [M,K] bf16 (ws)
                                                   const bf16_t* __restrict__ Bw,  // [N,K] bf16 (ws)
                                                   const float* __restrict__ xsq,  // [M]
                                                   const float* __restrict__ wsq,  // [N]
                                                   const float* __restrict__ bias,   // [N] fp32
                                                   const float* __restrict__ alpha,  // [1] fp32
                                                   float* __restrict__ out) {        // [M,N] fp32
    __shared__ bf16_t sA[6 * SEG];  // 48 KB, ring of 6 A half-segs (3 K-tiles)
    __shared__ bf16_t sB[6 * SEG];  // 48 KB

    const int tid = (int)threadIdx.x;
    const int lane = tid & 63;
    const int wv = tid >> 6;   // 0..7
    const int wm = wv >> 2;    // 0..1 : wave row (128-row band)
    const int wn = wv & 3;     // 0..3 : wave col (64-col band)
    const int bh = wn >> 1;    // B half (n band 0-127 / 128-255)

    const int bm = (int)blockIdx.x >> 3;  // 0..63
    const int bn = (int)blockIdx.x & 7;   // 0..7

    // fragment addressing (mfma_f32_16x16x32_bf16):
    //  A: lane holds A[m=lane&15][k=(lane>>4)*8+j]; B mirrored ([n][k])
    //  C/D: col=lane&15, row=(lane>>4)*4+reg   [m89/m91-verified]
    const int frm = lane & 15;
    const int jch = lane >> 4;  // k-chunk 0..3 within K=32

    // staging: thread t covers in-seg row t>>2, phys chunk t&3; global chunk
    // inverse-swizzled g = (t&3) ^ ((row>>1)&3) = (t&3) ^ ((t>>3)&3).
    // Seg row r, phys chunk c holds global chunk c ^ ((r>>1)&3); read of
    // global chunk jch reads phys jch ^ ((r>>1)&3)  -> 2-way bank alias only.
    const int st_r = tid >> 2;  // 0..127 in-seg row
    const int st_g = (tid & 3) ^ ((tid >> 3) & 3);
    const bf16_t* Ast = A + (size_t)(bm * BM + st_r) * K_DIM + st_g * 8;
    const bf16_t* Bst = Bw + (size_t)(bn * BN + st_r) * K_DIM + st_g * 8;
    // +h*128 rows for half 1
    const size_t h1off = (size_t)128 * K_DIM;

    f32x4 acc[8][4] = {};
    bf16x8 af[4], bf[4];

    // in-seg read offsets (elements): row*32 + (jch^((row>>1)&3))*8
#define AOFF(I) (((I)*16 + frm) * 32 + ((jch ^ ((((I)*16 + frm) >> 1) & 3)) * 8))
#define BOFF(J) ((bh ? 0 : 0), (((wn & 1) * 64 + (J)*16 + frm) * 32 + \
                 ((jch ^ ((((wn & 1) * 64 + (J)*16 + frm) >> 1) & 3)) * 8)))

#define SBAR asm volatile("s_barrier" ::: "memory");
#define LGKM0 asm volatile("s_waitcnt lgkmcnt(0)" ::: "memory");
#define VM4 asm volatile("s_waitcnt vmcnt(4)" ::: "memory");
#define VM0 asm volatile("s_waitcnt vmcnt(0)" ::: "memory");

    // prologue: tiles 0 and 1 (FIFO: t0 A0,B0,A1,B1 then t1) ; VM4 keeps t1.
    {
        async16(Ast, sA + 0 * SEG + tid * 8);          // A(0)h0 -> slot 0
        async16(Bst, sB + 0 * SEG + tid * 8);          // B(0)h0
        async16(Ast + h1off, sA + 1 * SEG + tid * 8);  // A(0)h1 -> slot 1
        async16(Bst + h1off, sB + 1 * SEG + tid * 8);  // B(0)h1
        async16(Ast + 32, sA + 2 * SEG + tid * 8);     // A(1)h0 -> slot 2
        async16(Bst + 32, sB + 2 * SEG + tid * 8);     // B(1)h0
        async16(Ast + h1off + 32, sA + 3 * SEG + tid * 8);  // A(1)h1 -> slot 3
        async16(Bst + h1off + 32, sB + 3 * SEG + tid * 8);  // B(1)h1
    }
    VM4
    SBAR

    int su = 0;  // u % 3
#pragma unroll 1
    for (int u = 0; u < KT; ++u) {
        const int sv = (su >= 1) ? (su - 1) : (su + 2);  // (u+2) % 3
        const bool st = (u + 2) < KT;
        const bf16_t* aB = sA + (su * 2 + wm) * SEG;
        const bf16_t* bB = sB + (su * 2 + bh) * SEG;
        const bf16_t* Asrc = Ast + (size_t)(u + 2) * 32;
        const bf16_t* Bsrc = Bst + (size_t)(u + 2) * 32;
        bf16_t* aD0 = sA + (sv * 2) * SEG + tid * 8;
        bf16_t* bD0 = sB + (sv * 2) * SEG + tid * 8;

        // ---- pE: quadrants i=0..3 ----
        af[0] = *(const bf16x8*)(aB + AOFF(0));
        af[1] = *(const bf16x8*)(aB + AOFF(1));
        af[2] = *(const bf16x8*)(aB + AOFF(2));
        af[3] = *(const bf16x8*)(aB + AOFF(3));
        bf[0] = *(const bf16x8*)(bB + BOFF(0));
        bf[1] = *(const bf16x8*)(bB + BOFF(1));
        bf[2] = *(const bf16x8*)(bB + BOFF(2));
        bf[3] = *(const bf16x8*)(bB + BOFF(3));
        if (st) { async16(Asrc, aD0); async16(Bsrc, bD0); }
        SBAR
        LGKM0
        __builtin_amdgcn_s_setprio(1);
#pragma unroll
        for (int i = 0; i < 4; ++i)
#pragma unroll
            for (int j = 0; j < 4; ++j)
                acc[i][j] = __builtin_amdgcn_mfma_f32_16x16x32_bf16(af[i], bf[j], acc[i][j], 0, 0, 0);
        __builtin_amdgcn_s_setprio(0);
        SBAR

        // ---- pO: quadrants i=4..7 ----
        af[0] = *(const bf16x8*)(aB + AOFF(4));
        af[1] = *(const bf16x8*)(aB + AOFF(5));
        af[2] = *(const bf16x8*)(aB + AOFF(6));
        af[3] = *(const bf16x8*)(aB + AOFF(7));
        if (st) { async16(Asrc + h1off, aD0 + SEG); async16(Bsrc + h1off, bD0 + SEG); }
        SBAR
        LGKM0
        __builtin_amdgcn_s_setprio(1);
#pragma unroll
        for (int i = 0; i < 4; ++i)
#pragma unroll
            for (int j = 0; j < 4; ++j)
                acc[4 + i][j] = __builtin_amdgcn_mfma_f32_16x16x32_bf16(af[i], bf[j], acc[4 + i][j], 0, 0, 0);
        __builtin_amdgcn_s_setprio(0);
        if (u < KT - 2) { VM4 } else { VM0 }
        SBAR

        su = (su == 2) ? 0 : (su + 1);
    }
#undef AOFF
#undef BOFF
#undef SBAR
#undef LGKM0
#undef VM4
#undef VM0

    // epilogue (fp32 stores)
    const float sc = powf(sqrtf((float)N_DIM) / logf(1.0f + (float)N_DIM), alpha[0]);
    float wsq_c[4], bias_c[4];
#pragma unroll
    for (int j = 0; j < 4; ++j) {
        const int col = bn * BN + wn * 64 + j * 16 + frm;
        wsq_c[j] = wsq[col];
        bias_c[j] = bias[col];
    }
#pragma unroll
    for (int i = 0; i < 8; ++i) {
#pragma unroll
        for (int r = 0; r < 4; ++r) {
            const int row = bm * BM + wm * 128 + i * 16 + jch * 4 + r;
            const float xs = xsq[row];
            float* orow = out + (size_t)row * N_DIM + bn * BN + wn * 64 + frm;
#pragma unroll
            for (int j = 0; j < 4; ++j) {
                const float y = acc[i][j][r];
                const float d = xs + wsq_c[j] - 2.0f * y + 1e-6f;
                orow[j * 16] = (y * y) / d * sc + bias_c[j];
            }
        }
    }
}

extern "C" void kernel_launch(void* const* d_in, const int* in_sizes, int n_in,
                              void* d_out, int out_size, void* d_ws, size_t ws_size,
                              hipStream_t stream) {
    (void)in_sizes; (void)n_in; (void)out_size; (void)ws_size;
    const float* x = (const float*)d_in[0];      // [16384, 2048] fp32
    const float* w = (const float*)d_in[1];      // [2048, 2048] fp32
    const float* alpha = (const float*)d_in[2];  // [1] fp32
    const float* bias = (const float*)d_in[3];   // [2048] fp32
    float* out = (float*)d_out;                  // [16384, 2048] fp32

    // ws layout: xb (33.5M bf16), wb (4.2M bf16), xsq (16384 f32), wsq (2048 f32)
    bf16_t* xb = (bf16_t*)d_ws;
    bf16_t* wb = xb + (size_t)M_DIM * K_DIM;
    float* xsq = (float*)(wb + (size_t)N_DIM * K_DIM);
    float* wsq = xsq + M_DIM;

    prep_convert<<<(M_DIM + N_DIM) / 8, 256, 0, stream>>>(x, w, xb, wb, xsq, wsq);
    yat_gemm<<<(M_DIM / BM) * (N_DIM / BN), 512, 0, stream>>>(xb, wb, xsq, wsq, bias, alpha, out);
}